// Round 5
// baseline (734.106 us; speedup 1.0000x reference)
//
#include <hip/hip_runtime.h>

constexpr int BATCH   = 16384;
constexpr int NCLS    = 1000;   // classes; each class = contiguous float4 of prototypes
constexpr int THREADS = 256;    // 4 waves
constexpr int BLOCKS  = BATCH / 2;  // 8192: one block per 2 rows -> 32 blocks/CU queued

__device__ __forceinline__ float softmin4(float4 v) {
    // d = -logsumexp(-x) = m - log(sum exp(m - x)), m = min(x); exp args in [-1,0]
    float m = fminf(fminf(v.x, v.y), fminf(v.z, v.w));
    float s = __expf(m - v.x) + __expf(m - v.y) + __expf(m - v.z) + __expf(m - v.w);
    return m - __logf(s);
}

__global__ __launch_bounds__(THREADS)
void mpl_kernel(const float* __restrict__ dist,
                const int*   __restrict__ labels,
                float*       __restrict__ acc,
                unsigned*    __restrict__ cnt,
                float*       __restrict__ out) {
    const int t    = threadIdx.x;
    const int row0 = blockIdx.x * 2;
    const int lab0 = labels[row0];
    const int lab1 = labels[row0 + 1];

    const float4* __restrict__ r0 =
        reinterpret_cast<const float4*>(dist) + (size_t)row0 * NCLS;
    const float4* __restrict__ r1 = r0 + NCLS;

    // classes handled by this thread (4 per row); tail: clamp + invalidate
    const int  c0 = t, c1 = t + 256, c2 = t + 512;
    const bool v3 = (t + 768 < NCLS);
    const int  c3 = v3 ? (t + 768) : (NCLS - 1);

    // --- issue ALL 8 loads before any compute (32 data VGPRs in flight) ---
    float4 a0 = r0[c0], a1 = r0[c1], a2 = r0[c2], a3 = r0[c3];
    float4 b0 = r1[c0], b1 = r1[c1], b2 = r1[c2], b3 = r1[c3];

    float d00 = softmin4(a0), d01 = softmin4(a1), d02 = softmin4(a2), d03 = softmin4(a3);
    float d10 = softmin4(b0), d11 = softmin4(b1), d12 = softmin4(b2), d13 = softmin4(b3);

    float s0 = d00 + d01 + d02 + (v3 ? d03 : 0.0f);
    float s1 = d10 + d11 + d12 + (v3 ? d13 : 0.0f);

    // in-class distance: exactly one (thread, slot) matches per row
    __shared__ float s_in[2];
    if      (c0 == lab0)       s_in[0] = d00;
    else if (c1 == lab0)       s_in[0] = d01;
    else if (c2 == lab0)       s_in[0] = d02;
    else if (v3 && c3 == lab0) s_in[0] = d03;
    if      (c0 == lab1)       s_in[1] = d10;
    else if (c1 == lab1)       s_in[1] = d11;
    else if (c2 == lab1)       s_in[1] = d12;
    else if (v3 && c3 == lab1) s_in[1] = d13;

    // dual 64-lane butterfly (the two reductions are independent -> overlap)
    #pragma unroll
    for (int off = 32; off; off >>= 1) {
        s0 += __shfl_xor(s0, off, 64);
        s1 += __shfl_xor(s1, off, 64);
    }

    __shared__ float s_w[4][2];
    const int lane = t & 63, wid = t >> 6;
    if (lane == 0) { s_w[wid][0] = s0; s_w[wid][1] = s1; }
    __syncthreads();

    if (t == 0) {
        float S0 = (s_w[0][0] + s_w[1][0]) + (s_w[2][0] + s_w[3][0]);
        float S1 = (s_w[0][1] + s_w[1][1]) + (s_w[2][1] + s_w[3][1]);
        float i0 = s_in[0], i1 = s_in[1];
        float o0 = (S0 - i0) * (1.0f / (NCLS - 1));
        float o1 = (S1 - i1) * (1.0f / (NCLS - 1));
        float part = (i0 * i0) / (o0 * o0) + (i1 * i1) / (o1 * o1);

        atomicAdd(acc, part);
        __threadfence();
        unsigned done = atomicAdd(cnt, 1u);
        if (done == gridDim.x - 1) {
            // all blocks' acc-adds happen-before their cnt increments
            float total = atomicAdd(acc, 0.0f);   // coherent device-scope read
            out[0] = total * (1.0f / BATCH);
        }
    }
}

extern "C" void kernel_launch(void* const* d_in, const int* in_sizes, int n_in,
                              void* d_out, int out_size, void* d_ws, size_t ws_size,
                              hipStream_t stream) {
    const float* dist   = (const float*)d_in[0];
    const int*   labels = (const int*)d_in[1];
    float*       acc    = (float*)d_ws;
    unsigned*    cnt    = (unsigned*)d_ws + 1;
    float*       out    = (float*)d_out;

    hipMemsetAsync(d_ws, 0, 8, stream);   // zero acc + counter (capture-safe)
    mpl_kernel<<<BLOCKS, THREADS, 0, stream>>>(dist, labels, acc, cnt, out);
}

// Round 6
// 348.981 us; speedup vs baseline: 2.1036x; 2.1036x over previous
//
#include <hip/hip_runtime.h>

constexpr int BATCH   = 16384;
constexpr int NCLS    = 1000;    // classes; each class = contiguous float4
constexpr int THREADS = 256;     // 4 waves -> 4 rows per block
constexpr int BLOCKS1 = BATCH / 4;   // 4096 blocks

// Kernel 1: one wave per row. No LDS, no barriers, no atomics.
// All 16 float4 loads issued into registers before any transcendental.
__global__ __launch_bounds__(THREADS, 4)
void mpl_rows(const float* __restrict__ dist,
              const int*   __restrict__ labels,
              float*       __restrict__ terms) {
    const int t    = threadIdx.x;
    const int lane = t & 63;
    const int wid  = t >> 6;
    const int row  = blockIdx.x * 4 + wid;

    const float4* __restrict__ rp =
        reinterpret_cast<const float4*>(dist) + (size_t)row * NCLS;
    const int lab = labels[row];

    // batch ALL row loads up front (64 data VGPRs in flight)
    const bool tailv = lane < (NCLS - 15 * 64);   // lane < 40 valid in iter 15
    float4 v[16];
    #pragma unroll
    for (int i = 0; i < 15; ++i) v[i] = rp[i * 64 + lane];
    v[15] = rp[tailv ? (15 * 64 + lane) : (NCLS - 1)];

    float sum = 0.0f, incls = 0.0f;
    #pragma unroll
    for (int i = 0; i < 16; ++i) {
        float4 x = v[i];
        // soft-min: d = m - log(sum exp(m - x)), m = min -> exp args in [-1, 0]
        float m = fminf(fminf(x.x, x.y), fminf(x.z, x.w));
        float s = __expf(m - x.x) + __expf(m - x.y) +
                  __expf(m - x.z) + __expf(m - x.w);
        float d = m - __logf(s);
        const int  c     = i * 64 + lane;
        const bool valid = (i < 15) || tailv;
        if (valid) {
            sum += d;
            if (c == lab) incls = d;   // exactly one (lane, i) matches per row
        }
    }

    // dual 64-lane butterfly; incls has a single nonzero lane -> sum recovers it
    #pragma unroll
    for (int off = 32; off; off >>= 1) {
        sum   += __shfl_xor(sum,   off, 64);
        incls += __shfl_xor(incls, off, 64);
    }

    if (lane == 0) {
        float om = (sum - incls) * (1.0f / (NCLS - 1));
        terms[row] = (incls * incls) / (om * om);
    }
}

// Kernel 2: single 1024-thread block reduces 16384 terms -> mean
__global__ __launch_bounds__(1024)
void mpl_reduce(const float* __restrict__ terms, float* __restrict__ out) {
    const int t = threadIdx.x;
    const float4* __restrict__ tp = reinterpret_cast<const float4*>(terms);
    float s = 0.0f;
    #pragma unroll
    for (int i = 0; i < 4; ++i) {            // 4096 float4 / 1024 threads
        float4 v = tp[t + i * 1024];
        s += (v.x + v.y) + (v.z + v.w);
    }
    #pragma unroll
    for (int off = 32; off; off >>= 1) s += __shfl_xor(s, off, 64);

    __shared__ float sw[16];
    const int lane = t & 63, wid = t >> 6;
    if (lane == 0) sw[wid] = s;
    __syncthreads();
    if (t == 0) {
        float tot = 0.0f;
        #pragma unroll
        for (int i = 0; i < 16; ++i) tot += sw[i];
        out[0] = tot * (1.0f / BATCH);
    }
}

extern "C" void kernel_launch(void* const* d_in, const int* in_sizes, int n_in,
                              void* d_out, int out_size, void* d_ws, size_t ws_size,
                              hipStream_t stream) {
    const float* dist   = (const float*)d_in[0];
    const int*   labels = (const int*)d_in[1];
    float*       terms  = (float*)d_ws;    // 16384 floats, fully overwritten
    float*       out    = (float*)d_out;

    mpl_rows<<<BLOCKS1, THREADS, 0, stream>>>(dist, labels, terms);
    mpl_reduce<<<1, 1024, 0, stream>>>(terms, out);
}

// Round 7
// 348.326 us; speedup vs baseline: 2.1075x; 1.0019x over previous
//
#include <hip/hip_runtime.h>

constexpr int BATCH   = 16384;
constexpr int NCLS    = 1000;    // classes; each class = contiguous float4
constexpr int THREADS = 256;     // 4 waves -> 4 rows per block
constexpr int BLOCKS1 = BATCH / 4;   // 4096 blocks

__device__ __forceinline__ float softmin4(float4 x) {
    // d = m - log(sum exp(m - x)), m = min -> exp args in [-1, 0]
    float m = fminf(fminf(x.x, x.y), fminf(x.z, x.w));
    float s = __expf(m - x.x) + __expf(m - x.y) +
              __expf(m - x.z) + __expf(m - x.w);
    return m - __logf(s);
}

// One wave per row; 8-deep software-pipelined load batches; no LDS/atomics.
// launch_bounds(256,8): cap 64 VGPR -> 8 waves/SIMD (32/CU) for latency hiding.
__global__ __launch_bounds__(THREADS, 8)
void mpl_rows(const float* __restrict__ dist,
              const int*   __restrict__ labels,
              float*       __restrict__ terms) {
    const int t    = threadIdx.x;
    const int lane = t & 63;
    const int wid  = t >> 6;
    const int row  = blockIdx.x * 4 + wid;

    const float4* __restrict__ rp =
        reinterpret_cast<const float4*>(dist) + (size_t)row * NCLS;
    const int lab = labels[row];

    const bool tailv = lane < (NCLS - 15 * 64);   // iter 15: lanes < 40 valid

    // batch 1: 8 loads in flight before any compute
    float4 v[8];
    #pragma unroll
    for (int i = 0; i < 8; ++i) v[i] = rp[i * 64 + lane];
    __builtin_amdgcn_sched_barrier(0);   // don't sink these loads past compute

    float sum = 0.0f, incls = 0.0f;

    // process batch 1; refill v[i] with iter i+8 immediately (stays 8-deep)
    #pragma unroll
    for (int i = 0; i < 8; ++i) {
        float4 x = v[i];
        const int nxt = (i + 8) * 64 + lane;              // iters 8..15
        v[i] = rp[(i < 7 || tailv) ? nxt : (NCLS - 1)];   // clamp tail of iter 15
        float d = softmin4(x);
        sum += d;
        if (i * 64 + lane == lab) incls = d;
    }

    // process batch 2
    #pragma unroll
    for (int i = 0; i < 8; ++i) {
        float d = softmin4(v[i]);
        const int  c     = (i + 8) * 64 + lane;
        const bool valid = (i < 7) || tailv;
        if (valid) {
            sum += d;
            if (c == lab) incls = d;   // exactly one (lane, iter) matches
        }
    }

    // dual butterfly; incls has one nonzero lane -> sum recovers it
    #pragma unroll
    for (int off = 32; off; off >>= 1) {
        sum   += __shfl_xor(sum,   off, 64);
        incls += __shfl_xor(incls, off, 64);
    }

    if (lane == 0) {
        float om = (sum - incls) * (1.0f / (NCLS - 1));
        terms[row] = (incls * incls) / (om * om);
    }
}

// Kernel 2: single 1024-thread block reduces 16384 terms -> mean
__global__ __launch_bounds__(1024)
void mpl_reduce(const float* __restrict__ terms, float* __restrict__ out) {
    const int t = threadIdx.x;
    const float4* __restrict__ tp = reinterpret_cast<const float4*>(terms);
    float s = 0.0f;
    #pragma unroll
    for (int i = 0; i < 4; ++i) {            // 4096 float4 / 1024 threads
        float4 v = tp[t + i * 1024];
        s += (v.x + v.y) + (v.z + v.w);
    }
    #pragma unroll
    for (int off = 32; off; off >>= 1) s += __shfl_xor(s, off, 64);

    __shared__ float sw[16];
    const int lane = t & 63, wid = t >> 6;
    if (lane == 0) sw[wid] = s;
    __syncthreads();
    if (t == 0) {
        float tot = 0.0f;
        #pragma unroll
        for (int i = 0; i < 16; ++i) tot += sw[i];
        out[0] = tot * (1.0f / BATCH);
    }
}

extern "C" void kernel_launch(void* const* d_in, const int* in_sizes, int n_in,
                              void* d_out, int out_size, void* d_ws, size_t ws_size,
                              hipStream_t stream) {
    const float* dist   = (const float*)d_in[0];
    const int*   labels = (const int*)d_in[1];
    float*       terms  = (float*)d_ws;    // 16384 floats, fully overwritten
    float*       out    = (float*)d_out;

    mpl_rows<<<BLOCKS1, THREADS, 0, stream>>>(dist, labels, terms);
    mpl_reduce<<<1, 1024, 0, stream>>>(terms, out);
}